// Round 3
// baseline (120.471 us; speedup 1.0000x reference)
//
#include <hip/hip_runtime.h>

#define NT 256

constexpr int L0 = 8192;
constexpr int N1 = 4099;   // (8192+7)>>1
constexpr int N2 = 2053;   // (4099+7)>>1
constexpr int N3 = 1030;   // (2053+7)>>1
constexpr int N4 = 518;    // (1030+7)>>1
constexpr int ROW_OUT = N4 + N4 + N3 + N2 + N1;  // 8218

// lo[i] = sum_j GLO[j] * xsym(2i-6+j)   (GLO = pywt db4 rec_lo = dec_lo reversed)
constexpr float GLO[8] = {
    0.23037781330885523f,  0.7148465705525415f,   0.6308807679295904f,
   -0.02798376941698385f, -0.18703481171888114f,  0.030841381835986965f,
    0.032883011666982945f, -0.010597401784997278f };
// hi[i] = sum_j GHI[j] * xsym(2i-6+j)   (GHI[j] = (-1)^j * rec_lo[7-j] = dec_hi reversed)
constexpr float GHI[8] = {
   -0.010597401784997278f, -0.032883011666982945f, 0.030841381835986965f,
    0.18703481171888114f,  -0.02798376941698385f,  -0.6308807679295904f,
    0.7148465705525415f,   -0.23037781330885523f };

// De-interleaved: a[2k]=E[k], a[2k+1]=O[k]. Window a_sym[2i-6+j]:
// even j -> E[i-3+j/2], odd j -> O[i-3+(j-1)/2].
// Pads (half-sample symmetric): E[-p]=O[p-1], O[-p]=E[p-1] (p=1..4);
// E[nE+t]=O[n-1-nE-t], O[nO+t]=E[n-1-nO-t].
__device__ __forceinline__ void set_pads(float* __restrict__ e, float* __restrict__ o,
                                         int n, int nE, int nO, int nout, int tid)
{
    if (tid < 4) {
        e[-1 - tid] = o[tid];
        o[-1 - tid] = e[tid];
        if (tid < nout - nE) e[nE + tid] = o[n - 1 - nE - tid];
        if (tid < nout - nO) o[nO + tid] = e[n - 1 - nO - tid];
    }
}

// Each thread: 4 consecutive outputs i0..i0+3 from 4 aligned float4 LDS reads.
// e,o interior pointers (16B aligned, 4 left pads + >=3 right pads valid).
template <bool LAST>
__device__ __forceinline__ void dwt_level_vec(const float* __restrict__ e,
                                              const float* __restrict__ o,
                                              int nout,
                                              float* __restrict__ eN,
                                              float* __restrict__ oN,
                                              float* __restrict__ loG,
                                              float* __restrict__ hiG, int tid)
{
    const int nv = nout & ~3;
    const float4* e4 = (const float4*)(e - 4);   // e4[k] = E[4k-4 .. 4k-1]
    const float4* o4 = (const float4*)(o - 4);
    for (int i0 = 4 * tid; i0 < nv; i0 += 4 * NT) {
        const int q = i0 >> 2;
        float4 eL = e4[q], eH = e4[q + 1];
        float4 oL = o4[q], oH = o4[q + 1];
        float cE[8] = {eL.x, eL.y, eL.z, eL.w, eH.x, eH.y, eH.z, eH.w};
        float cO[8] = {oL.x, oL.y, oL.z, oL.w, oH.x, oH.y, oH.z, oH.w};
        float lo[4], hi[4];
#pragma unroll
        for (int r = 0; r < 4; ++r) {
            float l = 0.f, h = 0.f;
#pragma unroll
            for (int m = 0; m < 4; ++m) {
                float ve = cE[r + 1 + m];
                float vo = cO[r + 1 + m];
                l = fmaf(GLO[2 * m], ve, l);
                l = fmaf(GLO[2 * m + 1], vo, l);
                h = fmaf(GHI[2 * m], ve, h);
                h = fmaf(GHI[2 * m + 1], vo, h);
            }
            lo[r] = l; hi[r] = h;
        }
        hiG[i0 + 0] = hi[0]; hiG[i0 + 1] = hi[1];
        hiG[i0 + 2] = hi[2]; hiG[i0 + 3] = hi[3];
        if (LAST) {
            loG[i0 + 0] = lo[0]; loG[i0 + 1] = lo[1];
            loG[i0 + 2] = lo[2]; loG[i0 + 3] = lo[3];
        } else {
            ((float2*)eN)[q] = make_float2(lo[0], lo[2]);  // cA[i0], cA[i0+2]
            ((float2*)oN)[q] = make_float2(lo[1], lo[3]);  // cA[i0+1], cA[i0+3]
        }
    }
    // ragged tail (<=3 windows), scalar
    const int rem = nout - nv;
    if (tid < rem) {
        const int i = nv + tid;
        float l = 0.f, h = 0.f;
#pragma unroll
        for (int m = 0; m < 4; ++m) {
            float ve = e[i - 3 + m];
            float vo = o[i - 3 + m];
            l = fmaf(GLO[2 * m], ve, l);
            l = fmaf(GLO[2 * m + 1], vo, l);
            h = fmaf(GHI[2 * m], ve, h);
            h = fmaf(GHI[2 * m + 1], vo, h);
        }
        hiG[i] = h;
        if (LAST) {
            loG[i] = l;
        } else {
            float* t = (i & 1) ? oN : eN;
            t[i >> 1] = l;
        }
    }
}

__global__ __launch_bounds__(NT) void wavedec4_db4(const float* __restrict__ x,
                                                   float* __restrict__ out)
{
    // interiors at +4 floats (16B aligned); 4 left pads, 4 right pads
    __shared__ __align__(16) float eA[4 + 4096 + 4], oA[4 + 4096 + 4];
    __shared__ __align__(16) float eB[4 + 2050 + 4], oB[4 + 2050 + 4];
    const int tid = threadIdx.x;
    const float* __restrict__ xr = x + blockIdx.x * (size_t)L0;
    float* __restrict__ outr = out + blockIdx.x * (size_t)ROW_OUT;
    float* E0 = eA + 4; float* O0 = oA + 4;
    float* E1 = eB + 4; float* O1 = oB + 4;

    // Stage row de-interleaved; fuse level-1 pads (computed from global x).
    const float4* x4 = (const float4*)xr;
    float2* e2 = (float2*)E0;
    float2* o2 = (float2*)O0;
    for (int idx = tid; idx < L0 / 4; idx += NT) {
        float4 v = x4[idx];
        e2[idx] = make_float2(v.x, v.z);
        o2[idx] = make_float2(v.y, v.w);
    }
    if (tid < 4) {
        E0[-1 - tid] = xr[2 * tid + 1];          // O0[tid]
        O0[-1 - tid] = xr[2 * tid];              // E0[tid]
        if (tid < 3) {
            E0[4096 + tid] = xr[8191 - 2 * tid]; // O0[4095-tid]
            O0[4096 + tid] = xr[8190 - 2 * tid]; // E0[4095-tid]
        }
    }
    __syncthreads();

    // L1: n=8192 -> (E1,O1); cD1 -> out[4119..)
    dwt_level_vec<false>(E0, O0, N1, E1, O1, nullptr, outr + (N4 + N4 + N3 + N2), tid);
    __syncthreads();
    set_pads(E1, O1, N1, 2050, 2049, N2, tid);
    __syncthreads();

    // L2: n=4099 -> (E0,O0); cD2 -> out[2066..)
    dwt_level_vec<false>(E1, O1, N2, E0, O0, nullptr, outr + (N4 + N4 + N3), tid);
    __syncthreads();
    set_pads(E0, O0, N2, 1027, 1026, N3, tid);
    __syncthreads();

    // L3: n=2053 -> (E1,O1); cD3 -> out[1036..)
    dwt_level_vec<false>(E0, O0, N3, E1, O1, nullptr, outr + (N4 + N4), tid);
    __syncthreads();
    set_pads(E1, O1, N3, 515, 515, N4, tid);
    __syncthreads();

    // L4: n=1030 -> cA4 = out[0..518), cD4 = out[518..1036)
    dwt_level_vec<true>(E1, O1, N4, nullptr, nullptr, outr, outr + N4, tid);
}

extern "C" void kernel_launch(void* const* d_in, const int* in_sizes, int n_in,
                              void* d_out, int out_size, void* d_ws, size_t ws_size,
                              hipStream_t stream) {
    const float* x = (const float*)d_in[0];
    float* out = (float*)d_out;
    const int rows = in_sizes[0] / L0;  // 64*32 = 2048
    wavedec4_db4<<<dim3(rows), dim3(NT), 0, stream>>>(x, out);
}

// Round 5
// 118.522 us; speedup vs baseline: 1.0164x; 1.0164x over previous
//
#include <hip/hip_runtime.h>

#define NT 256

constexpr int L0 = 8192;
constexpr int N1 = 4099;   // (8192+7)>>1
constexpr int N2 = 2053;   // (4099+7)>>1
constexpr int N3 = 1030;   // (2053+7)>>1
constexpr int N4 = 518;    // (1030+7)>>1
constexpr int ROW_OUT = N4 + N4 + N3 + N2 + N1;  // 8218

// lo[i] = sum_j GLO[j] * xsym(2i-6+j)   (GLO = pywt db4 rec_lo = dec_lo reversed)
constexpr float GLO[8] = {
    0.23037781330885523f,  0.7148465705525415f,   0.6308807679295904f,
   -0.02798376941698385f, -0.18703481171888114f,  0.030841381835986965f,
    0.032883011666982945f, -0.010597401784997278f };
// hi[i] = sum_j GHI[j] * xsym(2i-6+j)   (GHI[j] = (-1)^j * rec_lo[7-j] = dec_hi reversed)
constexpr float GHI[8] = {
   -0.010597401784997278f, -0.032883011666982945f, 0.030841381835986965f,
    0.18703481171888114f,  -0.02798376941698385f,  -0.6308807679295904f,
    0.7148465705525415f,   -0.23037781330885523f };

// De-interleaved: a[2k]=E[k], a[2k+1]=O[k]. Window a_sym[2i-6+j]:
// even j -> E[i-3+j/2], odd j -> O[i-3+(j-1)/2].
// Pad algebra (half-sample symmetric, edge repeated):
//   E[-1-t]=O[t], O[-1-t]=E[t];  E[nE+t]=O[n-1-nE-t], O[nO+t]=E[n-1-nO-t].
// Pointers carry GLOBAL level-index semantics (may be offset before the LDS
// array start); iLo is a multiple of 4 so ds_read_b128 stays 16B-aligned.
template <bool LAST>
__device__ __forceinline__ void level_vec(const float* __restrict__ e,
                                          const float* __restrict__ o,
                                          int iLo, int iHi,
                                          float* __restrict__ eN,
                                          float* __restrict__ oN,
                                          float* __restrict__ loG,
                                          float* __restrict__ hiG, int tid)
{
    const int span = iHi - iLo;
    const int nv = span & ~3;
    for (int v = 4 * tid; v < nv; v += 4 * NT) {
        const int i0 = iLo + v;
        float4 eL = *(const float4*)(e + i0 - 4);
        float4 eH = *(const float4*)(e + i0);
        float4 oL = *(const float4*)(o + i0 - 4);
        float4 oH = *(const float4*)(o + i0);
        float cE[8] = {eL.x, eL.y, eL.z, eL.w, eH.x, eH.y, eH.z, eH.w};
        float cO[8] = {oL.x, oL.y, oL.z, oL.w, oH.x, oH.y, oH.z, oH.w};
        float lo[4], hi[4];
#pragma unroll
        for (int r = 0; r < 4; ++r) {
            float l = 0.f, h = 0.f;
#pragma unroll
            for (int m = 0; m < 4; ++m) {
                float ve = cE[r + 1 + m];
                float vo = cO[r + 1 + m];
                l = fmaf(GLO[2 * m], ve, l);
                l = fmaf(GLO[2 * m + 1], vo, l);
                h = fmaf(GHI[2 * m], ve, h);
                h = fmaf(GHI[2 * m + 1], vo, h);
            }
            lo[r] = l; hi[r] = h;
        }
        hiG[i0 + 0] = hi[0]; hiG[i0 + 1] = hi[1];
        hiG[i0 + 2] = hi[2]; hiG[i0 + 3] = hi[3];
        if (LAST) {
            loG[i0 + 0] = lo[0]; loG[i0 + 1] = lo[1];
            loG[i0 + 2] = lo[2]; loG[i0 + 3] = lo[3];
        } else {
            *(float2*)(eN + (i0 >> 1)) = make_float2(lo[0], lo[2]);
            *(float2*)(oN + (i0 >> 1)) = make_float2(lo[1], lo[3]);
        }
    }
    const int rem = span - nv;   // <= 3
    if (tid < rem) {
        const int i = iLo + nv + tid;
        float l = 0.f, h = 0.f;
#pragma unroll
        for (int m = 0; m < 4; ++m) {
            float ve = e[i - 3 + m];
            float vo = o[i - 3 + m];
            l = fmaf(GLO[2 * m], ve, l);
            l = fmaf(GLO[2 * m + 1], vo, l);
            h = fmaf(GHI[2 * m], ve, h);
            h = fmaf(GHI[2 * m + 1], vo, h);
        }
        hiG[i] = h;
        if (LAST) {
            loG[i] = l;
        } else {
            float* t = (i & 1) ? oN : eN;
            t[i >> 1] = l;
        }
    }
}

// Two blocks per row. Left computes level ranges [0,2072)/[0,1036)/[0,518)/[0,259);
// right computes [1992,4099)/[1000,2053)/[504,1030)/[256,518). Overlaps are
// double-written with bit-identical values (same FMA order) — benign.
__global__ __launch_bounds__(NT) void wavedec4_db4_split(const float* __restrict__ x,
                                                         float* __restrict__ out)
{
    __shared__ __align__(16) float eA_s[2120], oA_s[2120];
    __shared__ __align__(16) float eB_s[1068], oB_s[1068];
    const int tid = threadIdx.x;
    const int row = blockIdx.x >> 1;
    const int half = blockIdx.x & 1;
    const float* __restrict__ xr = x + row * (size_t)L0;
    float* __restrict__ outr = out + row * (size_t)ROW_OUT;
    float* cA4 = outr;
    float* cD4 = outr + N4;
    float* cD3 = outr + 2 * N4;
    float* cD2 = outr + 2 * N4 + N3;
    float* cD1 = outr + 2 * N4 + N3 + N2;

    if (half == 0) {
        // ---- left half: all level bases at 0; 4 left sym pads ----
        float* E0 = eA_s + 4; float* O0 = oA_s + 4;
        float* E1 = eB_s + 4; float* O1 = oB_s + 4;
        // stage x[0, 4144)
        const float4* x4 = (const float4*)xr;
        float2* e2 = (float2*)E0; float2* o2 = (float2*)O0;
        for (int idx = tid; idx < 4144 / 4; idx += NT) {
            float4 vv = x4[idx];
            e2[idx] = make_float2(vv.x, vv.z);
            o2[idx] = make_float2(vv.y, vv.w);
        }
        if (tid < 4) {                       // E[-1-t]=O[t]=x[2t+1], O[-1-t]=E[t]=x[2t]
            E0[-1 - tid] = xr[2 * tid + 1];
            O0[-1 - tid] = xr[2 * tid];
        }
        __syncthreads();
        level_vec<false>(E0, O0, 0, 2072, E1, O1, nullptr, cD1, tid);   // L1
        __syncthreads();
        if (tid < 4) { E1[-1 - tid] = O1[tid]; O1[-1 - tid] = E1[tid]; }
        __syncthreads();
        level_vec<false>(E1, O1, 0, 1036, E0, O0, nullptr, cD2, tid);   // L2
        __syncthreads();
        if (tid < 4) { E0[-1 - tid] = O0[tid]; O0[-1 - tid] = E0[tid]; }
        __syncthreads();
        level_vec<false>(E0, O0, 0, 518, E1, O1, nullptr, cD3, tid);    // L3
        __syncthreads();
        if (tid < 4) { E1[-1 - tid] = O1[tid]; O1[-1 - tid] = E1[tid]; }
        __syncthreads();
        level_vec<true>(E1, O1, 0, 259, nullptr, nullptr, cA4, cD4, tid); // L4
    } else {
        // ---- right half: offset bases (all x4): E0@1988, E1@996, E2@500, E3@252 ----
        float* E0 = eA_s - 1988; float* O0 = oA_s - 1988;
        float* E1 = eB_s - 996;  float* O1 = oB_s - 996;
        // stage x[3976, 8192)  (4216 floats, 16B-aligned base)
        const float4* x4 = (const float4*)(xr + 3976);
        float2* e2 = (float2*)eA_s; float2* o2 = (float2*)oA_s;
        for (int idx = tid; idx < 4216 / 4; idx += NT) {
            float4 vv = x4[idx];
            e2[idx] = make_float2(vv.x, vv.z);
            o2[idx] = make_float2(vv.y, vv.w);
        }
        if (tid < 4) {                       // right sym pads: E[4096+t]=O[4095-t], O[4096+t]=E[4095-t]
            E0[4096 + tid] = xr[8191 - 2 * tid];
            O0[4096 + tid] = xr[8190 - 2 * tid];
        }
        __syncthreads();
        level_vec<false>(E0, O0, 1992, N1, E1, O1, nullptr, cD1, tid);  // L1
        __syncthreads();
        // level-1 right pads (n=4099, nE=2050, nO=2049):
        //   E1[2050+t]=O1[n-1-nE-t]=O1[2048-t];  O1[2049+t]=E1[n-1-nO-t]=E1[2049-t]
        if (tid < 3) E1[2050 + tid] = O1[2048 - tid];
        if (tid < 4) O1[2049 + tid] = E1[2049 - tid];
        __syncthreads();
        float* E2 = eA_s - 500; float* O2 = oA_s - 500;
        level_vec<false>(E1, O1, 1000, N2, E2, O2, nullptr, cD2, tid);  // L2
        __syncthreads();
        // level-2 right pads (n=2053, nE=1027, nO=1026):
        //   E2[1027+t]=O2[1025-t];  O2[1026+t]=E2[1026-t]
        if (tid < 3) E2[1027 + tid] = O2[1025 - tid];
        if (tid < 4) O2[1026 + tid] = E2[1026 - tid];
        __syncthreads();
        float* E3 = eB_s - 252; float* O3 = oB_s - 252;
        level_vec<false>(E2, O2, 504, N3, E3, O3, nullptr, cD3, tid);   // L3
        __syncthreads();
        // level-3 right pads (n=1030, nE=nO=515): E3[515+t]=O3[514-t]; O3[515+t]=E3[514-t]
        if (tid < 3) { E3[515 + tid] = O3[514 - tid]; O3[515 + tid] = E3[514 - tid]; }
        __syncthreads();
        level_vec<true>(E3, O3, 256, N4, nullptr, nullptr, cA4, cD4, tid); // L4
    }
}

extern "C" void kernel_launch(void* const* d_in, const int* in_sizes, int n_in,
                              void* d_out, int out_size, void* d_ws, size_t ws_size,
                              hipStream_t stream) {
    const float* x = (const float*)d_in[0];
    float* out = (float*)d_out;
    const int rows = in_sizes[0] / L0;  // 64*32 = 2048
    wavedec4_db4_split<<<dim3(rows * 2), dim3(NT), 0, stream>>>(x, out);
}